// Round 7
// baseline (110.048 us; speedup 1.0000x reference)
//
#include <hip/hip_runtime.h>
#include <hip/hip_bf16.h>

#define NXX 256
#define NG 32768
#define WID 128

typedef short bf16x8 __attribute__((ext_vector_type(8)));
typedef float f32x4 __attribute__((ext_vector_type(4)));
typedef unsigned int u32x4 __attribute__((ext_vector_type(4)));

__device__ __forceinline__ unsigned short rne_bf16(float x) {
    unsigned int u = __float_as_uint(x);
    return (unsigned short)((u + 0x7fffu + ((u >> 16) & 1u)) >> 16);
}

// ---------------------------------------------------------------------------
// Prep: pack Wg into A-operand fragment streams with k-axis PRE-PERMUTED by
// pi: k_full=(kc:2|g:2|j2:1|j10:2) -> ch=(kc:2|j2:1|g:2|j10:2).  This makes
// the next layer's B-fragment equal to the thread's own D registers (the
// GEMM is invariant under a common k-permutation of W and x).
// Lane lv elem j of stream e=(l*4+kc)*8+nt holds W[pi(32kc+8g+j)][16nt+(lv&15)].
// ---------------------------------------------------------------------------
__global__ __launch_bounds__(64) void prep_kernel(
    const float* __restrict__ Wg, unsigned short* __restrict__ Bfrag) {
    const int e  = blockIdx.x;       // 0..127
    const int lv = threadIdx.x;      // 0..63
    const int l  = e >> 5;
    const int kc = (e >> 3) & 3;
    const int nt = e & 7;
    const int n  = nt * 16 + (lv & 15);
    const int g  = lv >> 4;          // k-granule 0..3
#pragma unroll
    for (int j = 0; j < 8; ++j) {
        const int ch = kc * 32 + ((j >> 2) << 4) + (g << 2) + (j & 3);  // pi
        float v = Wg[(size_t)l * 16384 + (size_t)ch * WID + n];
        Bfrag[(size_t)e * 512 + lv * 8 + j] = rne_bf16(v);
    }
}

__device__ __forceinline__ unsigned int pack_bf2(float a, float b) {
    union { __hip_bfloat162 h2; unsigned int u; } cv;
    cv.h2 = __float22bfloat162_rn(make_float2(a, b));   // low16 = a
    return cv.u;
}

union fragu { bf16x8 f; u32x4 u; };

// ---------------------------------------------------------------------------
// Fused net, register-resident: D = mfma(A=W^T-frag(pi), B=X-frag) = H^T tile.
// Lane layout: node row = lane&15; thread owns cols {16nt + 4*(lane>>4) + r}.
// Rows m<8 -> batch b, m>=8 -> batch b+2, u = ublk + 8w + (m&7).
// pi-permuted W makes next-layer B-fragments = own D registers (no LDS!).
// Partner mix = shfl_xor 8 (uniform c1/c2), LN reduce = shfl_xor 16,32.
// No LDS, no barriers: waves fully independent.
// ---------------------------------------------------------------------------
__global__ __launch_bounds__(256) void fused_kernel(
    const float* __restrict__ u0, const float* __restrict__ P,
    const float* __restrict__ W_in, const float* __restrict__ b_in,
    const unsigned short* __restrict__ Bfrag,
    const float* __restrict__ bg, const float* __restrict__ gamma,
    const float* __restrict__ beta, const float* __restrict__ W_out,
    const float* __restrict__ b_out, float* __restrict__ out)
{
    const int tid  = threadIdx.x;
    const int w    = tid >> 6;
    const int lane = tid & 63;
    const int l15  = lane & 15;
    const int lhi  = lane >> 4;      // 0..3

    const int blk  = blockIdx.x;     // 0..2047
    const int b    = blk >> 10;      // 0 or 1; partner batch = b+2
    const int ublk = (blk & 1023) << 5;

    // ---- this lane's row ----
    const int uo  = l15 & 7;
    const int bb  = b + ((l15 >> 3) << 1);
    const int u   = ublk + 8 * w + uo;
    const int ix  = u >> 7;
    const int t   = u & 127;
    const bool isB2 = (l15 & 8) != 0;

    // degree coeffs (t-major graph indexing); uniform form: a = c1*pt + c2*h + bg
    float c1, c2;
    {
        int gi = u & 255, gt = u >> 8;
        int d  = (gi > 0) + (gi < 255) + (gt > 0) + (gt < 127);
        float deg = 2.f * (float)d + 1.f;
        c1 = isB2 ? 2.f * (float)d * rsqrtf(deg) : 0.f;
        c2 = isB2 ? 1.f / deg : 1.f;
    }

    // ---- features of my row ----
    float feat[7];
    {
        float s  = ((float)t + 0.5f) * 0.125f - 0.5f;
        float fs = floorf(s);
        int   t0 = (int)fs;
        float wt = s - fs;
        int t0c = t0 < 0 ? 0 : (t0 > 15 ? 15 : t0);
        int t1n = t0 + 1;
        int t1c = t1n < 0 ? 0 : (t1n > 15 ? 15 : t1n);
        const float* ur = u0 + ((size_t)bb * NXX + ix) * 16;
        feat[0] = ur[t0c] * (1.f - wt) + ur[t1c] * wt;
        feat[1] = P[bb * 4 + 0];
        feat[2] = P[bb * 4 + 1];
        feat[3] = P[bb * 4 + 2];
        feat[4] = P[bb * 4 + 3];
        feat[5] = (float)ix * (1.f / 255.f);
        feat[6] = (float)t  * (1.f / 127.f);
    }

    // ---- X0 = feat @ W_in + b_in, directly in D-layout ----
    float xres[8][4];
#pragma unroll
    for (int nt = 0; nt < 8; ++nt) {
        const int c = nt * 16 + 4 * lhi;
        float4 bi4 = *(const float4*)(b_in + c);
        float4 wf[7];
#pragma unroll
        for (int f = 0; f < 7; ++f) wf[f] = *(const float4*)(W_in + f * WID + c);
#pragma unroll
        for (int r = 0; r < 4; ++r) {
            float a = ((const float*)&bi4)[r];
#pragma unroll
            for (int f = 0; f < 7; ++f) a += feat[f] * ((const float*)&wf[f])[r];
            xres[nt][r] = a;
        }
    }

    // ======== 4 GCN layers, fully register-resident ========
    for (int l = 0; l < 4; ++l) {
        // ---- pack hi/lo B-fragments straight from xres registers ----
        fragu xh[4], xl[4];
#pragma unroll
        for (int kc = 0; kc < 4; ++kc) {
            unsigned int hp[4], lp[4];
#pragma unroll
            for (int hf = 0; hf < 2; ++hf) {
                float x0 = xres[2 * kc + hf][0], x1 = xres[2 * kc + hf][1];
                float x2 = xres[2 * kc + hf][2], x3 = xres[2 * kc + hf][3];
                unsigned int p0 = pack_bf2(x0, x1);
                unsigned int p1 = pack_bf2(x2, x3);
                float h0 = __uint_as_float(p0 << 16);
                float h1 = __uint_as_float(p0 & 0xffff0000u);
                float h2 = __uint_as_float(p1 << 16);
                float h3 = __uint_as_float(p1 & 0xffff0000u);
                hp[2 * hf]     = p0;
                hp[2 * hf + 1] = p1;
                lp[2 * hf]     = pack_bf2(x0 - h0, x1 - h1);
                lp[2 * hf + 1] = pack_bf2(x2 - h2, x3 - h3);
            }
            xh[kc].u = (u32x4){hp[0], hp[1], hp[2], hp[3]};
            xl[kc].u = (u32x4){lp[0], lp[1], lp[2], lp[3]};
        }

        // ---- MFMA: acc[nt] = W^T-tile(pi) * (Xhi + Xlo) ----
        f32x4 acc[8];
        const unsigned short* bp = Bfrag + (size_t)l * 16384 + lane * 8;
#pragma unroll
        for (int nt = 0; nt < 8; ++nt) {
            f32x4 a = {0.f, 0.f, 0.f, 0.f};
#pragma unroll
            for (int kc = 0; kc < 4; ++kc) {
                bf16x8 bh = *(const bf16x8*)(bp + (kc * 8 + nt) * 512);
                a = __builtin_amdgcn_mfma_f32_16x16x32_bf16(bh, xh[kc].f, a, 0, 0, 0);
                a = __builtin_amdgcn_mfma_f32_16x16x32_bf16(bh, xl[kc].f, a, 0, 0, 0);
            }
            acc[nt] = a;
        }

        // ---- epilogue: pair mix (shfl 8), +bg, LN (per-row), residual ReLU --
        float s = 0.f, q = 0.f;
#pragma unroll
        for (int nt = 0; nt < 8; ++nt) {
            float4 bg4 = *(const float4*)(bg + l * WID + nt * 16 + 4 * lhi);
#pragma unroll
            for (int r = 0; r < 4; ++r) {
                float h  = acc[nt][r];
                float pt = __shfl_xor(h, 8);
                float a  = fmaf(c1, pt, fmaf(c2, h, ((const float*)&bg4)[r]));
                acc[nt][r] = a;
                s += a;
                q = fmaf(a, a, q);
            }
        }
        s += __shfl_xor(s, 16);  q += __shfl_xor(q, 16);
        s += __shfl_xor(s, 32);  q += __shfl_xor(q, 32);
        float mu = s * (1.f / 128.f);
        float rs = rsqrtf(q * (1.f / 128.f) - mu * mu + 1e-5f);
#pragma unroll
        for (int nt = 0; nt < 8; ++nt) {
            const int c = nt * 16 + 4 * lhi;
            float4 g4 = *(const float4*)(gamma + l * WID + c);
            float4 e4 = *(const float4*)(beta  + l * WID + c);
#pragma unroll
            for (int r = 0; r < 4; ++r) {
                float nv = (acc[nt][r] - mu) * rs * ((const float*)&g4)[r]
                           + ((const float*)&e4)[r];
                xres[nt][r] = fmaxf(nv + xres[nt][r], 0.f);
            }
        }
    }

    // ======== out head ========
    float p = 0.f;
#pragma unroll
    for (int nt = 0; nt < 8; ++nt) {
        float4 wo4 = *(const float4*)(W_out + nt * 16 + 4 * lhi);
#pragma unroll
        for (int r = 0; r < 4; ++r) p += xres[nt][r] * ((const float*)&wo4)[r];
    }
    p += __shfl_xor(p, 16);
    p += __shfl_xor(p, 32);
    if (lhi == 0) out[(size_t)bb * NG + u] = p + b_out[0];
}

// ---------------------------------------------------------------------------
extern "C" void kernel_launch(void* const* d_in, const int* in_sizes, int n_in,
                              void* d_out, int out_size, void* d_ws, size_t ws_size,
                              hipStream_t stream) {
    const float* u0    = (const float*)d_in[0];
    const float* P     = (const float*)d_in[1];
    const float* W_in  = (const float*)d_in[2];
    const float* b_in  = (const float*)d_in[3];
    const float* Wg    = (const float*)d_in[4];
    const float* bg    = (const float*)d_in[5];
    const float* gamma = (const float*)d_in[6];
    const float* beta  = (const float*)d_in[7];
    const float* W_out = (const float*)d_in[8];
    const float* b_out = (const float*)d_in[9];

    unsigned short* Bfrag = (unsigned short*)d_ws;   // 128 KB

    prep_kernel<<<128, 64, 0, stream>>>(Wg, Bfrag);
    fused_kernel<<<2048, 256, 0, stream>>>(
        u0, P, W_in, b_in, Bfrag, bg, gamma, beta, W_out, b_out, (float*)d_out);
}

// Round 8
// 97.758 us; speedup vs baseline: 1.1257x; 1.1257x over previous
//
#include <hip/hip_runtime.h>
#include <hip/hip_bf16.h>

#define NXX 256
#define NG 32768
#define WID 128
#define STRW 68   // LDS row stride in u32 words (odd*4: 2-4 way banks, 16B-aligned)

typedef short bf16x8 __attribute__((ext_vector_type(8)));
typedef float f32x4 __attribute__((ext_vector_type(4)));

__device__ __forceinline__ unsigned short rne_bf16(float x) {
    unsigned int u = __float_as_uint(x);
    return (unsigned short)((u + 0x7fffu + ((u >> 16) & 1u)) >> 16);
}

// ---------------------------------------------------------------------------
// Prep: pack Wg (4 layers of [128 k][128 n] fp32) into fragment-linear bf16
// streams. Lane l of stream e=(l*4+kc)*8+nt holds W[kc*32+(l>>4)*8+j][nt*16+(l&15)].
// Used as the *A* operand of mfma (W^T tile): A[m'=l&15][k=(l>>4)*8+j].
// ---------------------------------------------------------------------------
__global__ __launch_bounds__(64) void prep_kernel(
    const float* __restrict__ Wg, unsigned short* __restrict__ Bfrag) {
    const int e  = blockIdx.x;       // 0..127
    const int lv = threadIdx.x;      // 0..63
    const int l  = e >> 5;
    const int kc = (e >> 3) & 3;
    const int nt = e & 7;
    const int n  = nt * 16 + (lv & 15);
    const int kb = kc * 32 + ((lv >> 4) << 3);
#pragma unroll
    for (int j = 0; j < 8; ++j) {
        float v = Wg[(size_t)l * 16384 + (size_t)(kb + j) * WID + n];
        Bfrag[(size_t)e * 512 + lv * 8 + j] = rne_bf16(v);
    }
}

__device__ __forceinline__ unsigned int pack_bf2(float a, float b) {
    union { __hip_bfloat162 h2; unsigned int u; } cv;
    cv.h2 = __float22bfloat162_rn(make_float2(a, b));   // low16 = a (even col)
    return cv.u;
}

// ---------------------------------------------------------------------------
// Fused net, swapped-operand MFMA: D = mfma(A=W^T-frag, B=X-frag) = H^T tile.
// r6 structure (best measured: the LDS round-trip decouples pack->MFMA and
// lets the compiler hide Bfrag L2 latency — r7's register-only variant
// regressed 84->110us). Single-precision change: x is packed to PLAIN bf16
// (no hi/lo split): halves MFMA count, LDS traffic, and pack VALU.
// Lane layout: row m = lane&15 (wave-private 16 rows), thread owns cols
// {16nt + 4*(lane>>4) + r}. Rows m<8 -> batch b, m>=8 -> batch b+2,
// u = ublk + 8w + (m&7).  Partner mix = shfl_xor 8, LN reduce = shfl_xor 16,32.
// X staged per-wave in PRIVATE LDS slices -> NO barriers (waves drift; one
// wave's epilogue VALU hides another's MFMA/L2 latency, m114 overlap).
// ---------------------------------------------------------------------------
__global__ __launch_bounds__(256) void fused_kernel(
    const float* __restrict__ u0, const float* __restrict__ P,
    const float* __restrict__ W_in, const float* __restrict__ b_in,
    const unsigned short* __restrict__ Bfrag,
    const float* __restrict__ bg, const float* __restrict__ gamma,
    const float* __restrict__ beta, const float* __restrict__ W_out,
    const float* __restrict__ b_out, float* __restrict__ out)
{
    __shared__ unsigned int XsH[4][16 * STRW];   // 17408 B

    const int tid  = threadIdx.x;
    const int w    = tid >> 6;
    const int lane = tid & 63;
    const int l15  = lane & 15;
    const int lhi  = lane >> 4;      // 0..3

    const int blk  = blockIdx.x;     // 0..2047
    const int b    = blk >> 10;      // 0 or 1; partner batch = b+2
    const int ublk = (blk & 1023) << 5;

    // ---- this lane's row ----
    const int uo  = l15 & 7;
    const int bb  = b + ((l15 >> 3) << 1);
    const int u   = ublk + 8 * w + uo;
    const int ix  = u >> 7;
    const int t   = u & 127;
    const bool isB2 = (l15 & 8) != 0;

    // degree coeffs (t-major graph indexing); uniform: a = c1*pt + c2*h + bg
    float c1, c2;
    {
        int gi = u & 255, gt = u >> 8;
        int d  = (gi > 0) + (gi < 255) + (gt > 0) + (gt < 127);
        float deg = 2.f * (float)d + 1.f;
        c1 = isB2 ? 2.f * (float)d * rsqrtf(deg) : 0.f;
        c2 = isB2 ? 1.f / deg : 1.f;
    }

    // ---- features of my row ----
    float feat[7];
    {
        float s  = ((float)t + 0.5f) * 0.125f - 0.5f;
        float fs = floorf(s);
        int   t0 = (int)fs;
        float wt = s - fs;
        int t0c = t0 < 0 ? 0 : (t0 > 15 ? 15 : t0);
        int t1n = t0 + 1;
        int t1c = t1n < 0 ? 0 : (t1n > 15 ? 15 : t1n);
        const float* ur = u0 + ((size_t)bb * NXX + ix) * 16;
        feat[0] = ur[t0c] * (1.f - wt) + ur[t1c] * wt;
        feat[1] = P[bb * 4 + 0];
        feat[2] = P[bb * 4 + 1];
        feat[3] = P[bb * 4 + 2];
        feat[4] = P[bb * 4 + 3];
        feat[5] = (float)ix * (1.f / 255.f);
        feat[6] = (float)t  * (1.f / 127.f);
    }

    // ---- X0 = feat @ W_in + b_in, directly in D-layout ----
    float xres[8][4];
#pragma unroll
    for (int nt = 0; nt < 8; ++nt) {
        const int c = nt * 16 + 4 * lhi;
        float4 bi4 = *(const float4*)(b_in + c);
        float4 wf[7];
#pragma unroll
        for (int f = 0; f < 7; ++f) wf[f] = *(const float4*)(W_in + f * WID + c);
#pragma unroll
        for (int r = 0; r < 4; ++r) {
            float a = ((const float*)&bi4)[r];
#pragma unroll
            for (int f = 0; f < 7; ++f) a += feat[f] * ((const float*)&wf[f])[r];
            xres[nt][r] = a;
        }
    }

    unsigned int* Hrow = &XsH[w][l15 * STRW];

    // ======== 4 GCN layers (barrier-free) ========
    for (int l = 0; l < 4; ++l) {
        // ---- pack bf16 and store (one b64 per nt) ----
#pragma unroll
        for (int nt = 0; nt < 8; ++nt) {
            unsigned int p0 = pack_bf2(xres[nt][0], xres[nt][1]);
            unsigned int p1 = pack_bf2(xres[nt][2], xres[nt][3]);
            *(uint2*)(Hrow + 8 * nt + 2 * lhi) = make_uint2(p0, p1);
        }

        // ---- read X fragments (B-operand layout: row l15, k = 32kc+8lhi+j) --
        bf16x8 xh[4];
#pragma unroll
        for (int kc = 0; kc < 4; ++kc)
            xh[kc] = *(const bf16x8*)(Hrow + 16 * kc + 4 * lhi);

        // ---- MFMA: acc[nt] = W^T-tile * X ----
        f32x4 acc[8];
        const unsigned short* bp = Bfrag + (size_t)l * 16384 + lane * 8;
        __builtin_amdgcn_s_setprio(1);
#pragma unroll
        for (int nt = 0; nt < 8; ++nt) {
            f32x4 a = {0.f, 0.f, 0.f, 0.f};
#pragma unroll
            for (int kc = 0; kc < 4; ++kc) {
                bf16x8 bh = *(const bf16x8*)(bp + (kc * 8 + nt) * 512);
                a = __builtin_amdgcn_mfma_f32_16x16x32_bf16(bh, xh[kc], a, 0, 0, 0);
            }
            acc[nt] = a;
        }
        __builtin_amdgcn_s_setprio(0);

        // ---- epilogue: pair mix (shfl 8), +bg, LN (per-row), residual ReLU --
        float s = 0.f, q = 0.f;
#pragma unroll
        for (int nt = 0; nt < 8; ++nt) {
            float4 bg4 = *(const float4*)(bg + l * WID + nt * 16 + 4 * lhi);
#pragma unroll
            for (int r = 0; r < 4; ++r) {
                float h  = acc[nt][r];
                float pt = __shfl_xor(h, 8);
                float a  = fmaf(c1, pt, fmaf(c2, h, ((const float*)&bg4)[r]));
                acc[nt][r] = a;
                s += a;
                q = fmaf(a, a, q);
            }
        }
        s += __shfl_xor(s, 16);  q += __shfl_xor(q, 16);
        s += __shfl_xor(s, 32);  q += __shfl_xor(q, 32);
        float mu = s * (1.f / 128.f);
        float rs = rsqrtf(q * (1.f / 128.f) - mu * mu + 1e-5f);
#pragma unroll
        for (int nt = 0; nt < 8; ++nt) {
            const int c = nt * 16 + 4 * lhi;
            float4 g4 = *(const float4*)(gamma + l * WID + c);
            float4 e4 = *(const float4*)(beta  + l * WID + c);
#pragma unroll
            for (int r = 0; r < 4; ++r) {
                float nv = fmaf((acc[nt][r] - mu) * rs, ((const float*)&g4)[r],
                                ((const float*)&e4)[r]);
                xres[nt][r] = fmaxf(nv + xres[nt][r], 0.f);
            }
        }
        // no barrier: next layer's stores touch only this wave's own LDS rows,
        // ordered after this layer's reads by within-wave DS dependencies.
    }

    // ======== out head ========
    float p = 0.f;
#pragma unroll
    for (int nt = 0; nt < 8; ++nt) {
        float4 wo4 = *(const float4*)(W_out + nt * 16 + 4 * lhi);
#pragma unroll
        for (int r = 0; r < 4; ++r) p += xres[nt][r] * ((const float*)&wo4)[r];
    }
    p += __shfl_xor(p, 16);
    p += __shfl_xor(p, 32);
    if (lhi == 0) out[(size_t)bb * NG + u] = p + b_out[0];
}

// ---------------------------------------------------------------------------
extern "C" void kernel_launch(void* const* d_in, const int* in_sizes, int n_in,
                              void* d_out, int out_size, void* d_ws, size_t ws_size,
                              hipStream_t stream) {
    const float* u0    = (const float*)d_in[0];
    const float* P     = (const float*)d_in[1];
    const float* W_in  = (const float*)d_in[2];
    const float* b_in  = (const float*)d_in[3];
    const float* Wg    = (const float*)d_in[4];
    const float* bg    = (const float*)d_in[5];
    const float* gamma = (const float*)d_in[6];
    const float* beta  = (const float*)d_in[7];
    const float* W_out = (const float*)d_in[8];
    const float* b_out = (const float*)d_in[9];

    unsigned short* Bfrag = (unsigned short*)d_ws;   // 128 KB

    prep_kernel<<<128, 64, 0, stream>>>(Wg, Bfrag);
    fused_kernel<<<2048, 256, 0, stream>>>(
        u0, P, W_in, b_in, Bfrag, bg, gamma, beta, W_out, b_out, (float*)d_out);
}

// Round 9
// 62.253 us; speedup vs baseline: 1.7677x; 1.5703x over previous
//
#include <hip/hip_runtime.h>
#include <hip/hip_bf16.h>

#define NXX 256
#define NG 32768
#define WID 128
#define STRW 68   // LDS row stride in u32 words (odd*4: aligned b128, spread banks)

typedef short bf16x8 __attribute__((ext_vector_type(8)));
typedef float f32x4 __attribute__((ext_vector_type(4)));

__device__ __forceinline__ unsigned short rne_bf16(float x) {
    unsigned int u = __float_as_uint(x);
    return (unsigned short)((u + 0x7fffu + ((u >> 16) & 1u)) >> 16);
}

// ---------------------------------------------------------------------------
// Prep: pack Wg (4 layers of [128 k][128 n] fp32) into fragment-linear bf16
// streams. Lane l of stream e=(l*4+kc)*8+nt holds W[kc*32+(l>>4)*8+j][nt*16+(l&15)].
// Used as the *A* operand of mfma (W^T tile).
// ---------------------------------------------------------------------------
__global__ __launch_bounds__(64) void prep_kernel(
    const float* __restrict__ Wg, unsigned short* __restrict__ Bfrag) {
    const int e  = blockIdx.x;       // 0..127
    const int lv = threadIdx.x;      // 0..63
    const int l  = e >> 5;
    const int kc = (e >> 3) & 3;
    const int nt = e & 7;
    const int n  = nt * 16 + (lv & 15);
    const int kb = kc * 32 + ((lv >> 4) << 3);
#pragma unroll
    for (int j = 0; j < 8; ++j) {
        float v = Wg[(size_t)l * 16384 + (size_t)(kb + j) * WID + n];
        Bfrag[(size_t)e * 512 + lv * 8 + j] = rne_bf16(v);
    }
}

__device__ __forceinline__ unsigned int pack_bf2(float a, float b) {
    union { __hip_bfloat162 h2; unsigned int u; } cv;
    cv.h2 = __float22bfloat162_rn(make_float2(a, b));   // low16 = a (even col)
    return cv.u;
}

// ---------------------------------------------------------------------------
// Fused net. Each wave owns 16 NODES (u = ublk + 16w + (lane&15)) and computes
// TWO MFMA tiles per layer: tile0 = those nodes in batch b, tile1 = batch b+2.
// Same lane&15 -> same u in both tiles, so the graph pair-mix
//   a0 = h0 + bg;  a1 = c1*h0 + c2*h1 + bg
// is REGISTER-LOCAL (zero shuffles; r8's 32 ds_bpermute/layer eliminated).
// Bfrag loads shared by both tiles (L2 traffic halved); two independent
// MFMA/epilogue chains give ~2x ILP on every latency chain.
// LDS round-trip for B-fragment relayout kept (r6-proven; r7 showed the
// register-only path serializes load->mfma). No barriers: wave-private slices.
// ---------------------------------------------------------------------------
__global__ __launch_bounds__(256) void fused_kernel(
    const float* __restrict__ u0, const float* __restrict__ P,
    const float* __restrict__ W_in, const float* __restrict__ b_in,
    const unsigned short* __restrict__ Bfrag,
    const float* __restrict__ bg, const float* __restrict__ gamma,
    const float* __restrict__ beta, const float* __restrict__ W_out,
    const float* __restrict__ b_out, float* __restrict__ out)
{
    __shared__ unsigned int XsH[8][16 * STRW];   // 34816 B

    const int tid  = threadIdx.x;
    const int w    = tid >> 6;
    const int lane = tid & 63;
    const int l15  = lane & 15;
    const int lhi  = lane >> 4;      // 0..3

    const int blk  = blockIdx.x;     // 0..1023
    const int b    = blk >> 9;       // 0 or 1; partner batch = b+2
    const int ublk = (blk & 511) << 6;

    const int u  = ublk + 16 * w + l15;
    const int ix = u >> 7;
    const int t  = u & 127;

    // degree coeffs (t-major graph indexing), per-lane
    float c1, c2;
    {
        int gi = u & 255, gt = u >> 8;
        int d  = (gi > 0) + (gi < 255) + (gt > 0) + (gt < 127);
        float deg = 2.f * (float)d + 1.f;
        c1 = 2.f * (float)d * rsqrtf(deg);
        c2 = 1.f / deg;
    }

    // ---- features of node u for batch b (A) and b+2 (B) ----
    float featA[7], featB[7];
    {
        float s  = ((float)t + 0.5f) * 0.125f - 0.5f;
        float fs = floorf(s);
        int   t0 = (int)fs;
        float wt = s - fs;
        int t0c = t0 < 0 ? 0 : (t0 > 15 ? 15 : t0);
        int t1n = t0 + 1;
        int t1c = t1n < 0 ? 0 : (t1n > 15 ? 15 : t1n);
        const float* urA = u0 + ((size_t)b * NXX + ix) * 16;
        const float* urB = u0 + ((size_t)(b + 2) * NXX + ix) * 16;
        featA[0] = urA[t0c] * (1.f - wt) + urA[t1c] * wt;
        featB[0] = urB[t0c] * (1.f - wt) + urB[t1c] * wt;
#pragma unroll
        for (int f = 0; f < 4; ++f) {
            featA[1 + f] = P[b * 4 + f];
            featB[1 + f] = P[(b + 2) * 4 + f];
        }
        featA[5] = featB[5] = (float)ix * (1.f / 255.f);
        featA[6] = featB[6] = (float)t  * (1.f / 127.f);
    }

    // ---- X0 = feat @ W_in + b_in for both tiles (shared W_in loads) ----
    float xr0[8][4], xr1[8][4];
#pragma unroll
    for (int nt = 0; nt < 8; ++nt) {
        const int c = nt * 16 + 4 * lhi;
        float4 bi4 = *(const float4*)(b_in + c);
        float4 wf[7];
#pragma unroll
        for (int f = 0; f < 7; ++f) wf[f] = *(const float4*)(W_in + f * WID + c);
#pragma unroll
        for (int r = 0; r < 4; ++r) {
            float a0 = ((const float*)&bi4)[r];
            float a1 = a0;
#pragma unroll
            for (int f = 0; f < 7; ++f) {
                float wv = ((const float*)&wf[f])[r];
                a0 = fmaf(featA[f], wv, a0);
                a1 = fmaf(featB[f], wv, a1);
            }
            xr0[nt][r] = a0;
            xr1[nt][r] = a1;
        }
    }

    unsigned int* Hrow0 = &XsH[2 * w][l15 * STRW];
    unsigned int* Hrow1 = &XsH[2 * w + 1][l15 * STRW];

    // ======== 4 GCN layers (barrier-free) ========
    for (int l = 0; l < 4; ++l) {
        // ---- pack bf16 and store both tiles (one b64 per nt per tile) ----
#pragma unroll
        for (int nt = 0; nt < 8; ++nt) {
            unsigned int p0 = pack_bf2(xr0[nt][0], xr0[nt][1]);
            unsigned int p1 = pack_bf2(xr0[nt][2], xr0[nt][3]);
            *(uint2*)(Hrow0 + 8 * nt + 2 * lhi) = make_uint2(p0, p1);
            unsigned int q0 = pack_bf2(xr1[nt][0], xr1[nt][1]);
            unsigned int q1 = pack_bf2(xr1[nt][2], xr1[nt][3]);
            *(uint2*)(Hrow1 + 8 * nt + 2 * lhi) = make_uint2(q0, q1);
        }

        // ---- read X fragments (B-operand layout: row l15, k = 32kc+8lhi+j) --
        bf16x8 xh0[4], xh1[4];
#pragma unroll
        for (int kc = 0; kc < 4; ++kc) {
            xh0[kc] = *(const bf16x8*)(Hrow0 + 16 * kc + 4 * lhi);
            xh1[kc] = *(const bf16x8*)(Hrow1 + 16 * kc + 4 * lhi);
        }

        // ---- MFMA both tiles, sharing each bh load ----
        f32x4 acc0[8], acc1[8];
        const unsigned short* bp = Bfrag + (size_t)l * 16384 + lane * 8;
#pragma unroll
        for (int nt = 0; nt < 8; ++nt) {
            f32x4 a0 = {0.f, 0.f, 0.f, 0.f};
            f32x4 a1 = {0.f, 0.f, 0.f, 0.f};
#pragma unroll
            for (int kc = 0; kc < 4; ++kc) {
                bf16x8 bh = *(const bf16x8*)(bp + (kc * 8 + nt) * 512);
                a0 = __builtin_amdgcn_mfma_f32_16x16x32_bf16(bh, xh0[kc], a0, 0, 0, 0);
                a1 = __builtin_amdgcn_mfma_f32_16x16x32_bf16(bh, xh1[kc], a1, 0, 0, 0);
            }
            acc0[nt] = a0;
            acc1[nt] = a1;
        }

        // ---- epilogue: REGISTER-LOCAL pair mix, +bg, LN, residual ReLU ----
        float s0 = 0.f, q0 = 0.f, s1 = 0.f, q1 = 0.f;
#pragma unroll
        for (int nt = 0; nt < 8; ++nt) {
            float4 bg4 = *(const float4*)(bg + l * WID + nt * 16 + 4 * lhi);
#pragma unroll
            for (int r = 0; r < 4; ++r) {
                float bgr = ((const float*)&bg4)[r];
                float h0 = acc0[nt][r];
                float h1 = acc1[nt][r];
                float a0 = h0 + bgr;                          // batch b (deg 1)
                float a1 = fmaf(c1, h0, fmaf(c2, h1, bgr));   // batch b+2
                acc0[nt][r] = a0;
                acc1[nt][r] = a1;
                s0 += a0;  q0 = fmaf(a0, a0, q0);
                s1 += a1;  q1 = fmaf(a1, a1, q1);
            }
        }
        s0 += __shfl_xor(s0, 16);  q0 += __shfl_xor(q0, 16);
        s1 += __shfl_xor(s1, 16);  q1 += __shfl_xor(q1, 16);
        s0 += __shfl_xor(s0, 32);  q0 += __shfl_xor(q0, 32);
        s1 += __shfl_xor(s1, 32);  q1 += __shfl_xor(q1, 32);
        float mu0 = s0 * (1.f / 128.f);
        float mu1 = s1 * (1.f / 128.f);
        float rs0 = rsqrtf(q0 * (1.f / 128.f) - mu0 * mu0 + 1e-5f);
        float rs1 = rsqrtf(q1 * (1.f / 128.f) - mu1 * mu1 + 1e-5f);
#pragma unroll
        for (int nt = 0; nt < 8; ++nt) {
            const int c = nt * 16 + 4 * lhi;
            float4 g4 = *(const float4*)(gamma + l * WID + c);
            float4 e4 = *(const float4*)(beta  + l * WID + c);
#pragma unroll
            for (int r = 0; r < 4; ++r) {
                float gv = ((const float*)&g4)[r];
                float ev = ((const float*)&e4)[r];
                float n0 = fmaf((acc0[nt][r] - mu0) * rs0, gv, ev);
                float n1 = fmaf((acc1[nt][r] - mu1) * rs1, gv, ev);
                xr0[nt][r] = fmaxf(n0 + xr0[nt][r], 0.f);
                xr1[nt][r] = fmaxf(n1 + xr1[nt][r], 0.f);
            }
        }
        // no barrier: wave-private LDS slices; within-wave DS deps order them.
    }

    // ======== out head: two rows per lane ========
    float p0 = 0.f, p1 = 0.f;
#pragma unroll
    for (int nt = 0; nt < 8; ++nt) {
        float4 wo4 = *(const float4*)(W_out + nt * 16 + 4 * lhi);
#pragma unroll
        for (int r = 0; r < 4; ++r) {
            float wv = ((const float*)&wo4)[r];
            p0 = fmaf(xr0[nt][r], wv, p0);
            p1 = fmaf(xr1[nt][r], wv, p1);
        }
    }
    p0 += __shfl_xor(p0, 16);  p1 += __shfl_xor(p1, 16);
    p0 += __shfl_xor(p0, 32);  p1 += __shfl_xor(p1, 32);
    if (lhi == 0) {
        float bo = b_out[0];
        out[(size_t)b * NG + u]       = p0 + bo;
        out[(size_t)(b + 2) * NG + u] = p1 + bo;
    }
}

// ---------------------------------------------------------------------------
extern "C" void kernel_launch(void* const* d_in, const int* in_sizes, int n_in,
                              void* d_out, int out_size, void* d_ws, size_t ws_size,
                              hipStream_t stream) {
    const float* u0    = (const float*)d_in[0];
    const float* P     = (const float*)d_in[1];
    const float* W_in  = (const float*)d_in[2];
    const float* b_in  = (const float*)d_in[3];
    const float* Wg    = (const float*)d_in[4];
    const float* bg    = (const float*)d_in[5];
    const float* gamma = (const float*)d_in[6];
    const float* beta  = (const float*)d_in[7];
    const float* W_out = (const float*)d_in[8];
    const float* b_out = (const float*)d_in[9];

    unsigned short* Bfrag = (unsigned short*)d_ws;   // 128 KB

    prep_kernel<<<128, 64, 0, stream>>>(Wg, Bfrag);
    fused_kernel<<<1024, 256, 0, stream>>>(
        u0, P, W_in, b_in, Bfrag, bg, gamma, beta, W_out, b_out, (float*)d_out);
}